// Round 9
// baseline (475.458 us; speedup 1.0000x reference)
//
#include <hip/hip_runtime.h>

typedef _Float16 half8 __attribute__((ext_vector_type(8)));
typedef float f32x4 __attribute__((ext_vector_type(4)));

static constexpr int D = 1024;       // VQ_C == C_IN
static constexpr int NCODE = 2048;   // codebook size
static constexpr int MTOK = 16384;   // B * L = 8 * 2048
static constexpr int KIN = 2048;     // C_IN * DS
static constexpr int TLEN = 4096;
static constexpr int CAP = 2048;     // max rescored tokens (est. ~250 flagged)
#define TAU 0.4f

__device__ __forceinline__ void gload16(const void* g, void* l) {
  __builtin_amdgcn_global_load_lds(
      (const __attribute__((address_space(1))) void*)g,
      (__attribute__((address_space(3))) void*)l, 16, 0, 0);
}

__device__ __forceinline__ float key_to_f32(unsigned u) {
  unsigned bits = (u & 0x80000000u) ? (u & 0x7FFFFFFFu) : ~u;
  return __uint_as_float(bits);
}
__device__ __forceinline__ unsigned f32_to_key(float f) {
  unsigned ub = __float_as_uint(f);
  return (ub & 0x80000000u) ? ~ub : (ub | 0x80000000u);
}

// ---------------- pack kernels ----------------
__global__ __launch_bounds__(256) void k_pack_x(const float* __restrict__ x,
                                                _Float16* __restrict__ xh,
                                                _Float16* __restrict__ xl) {
  __shared__ float lds[32][65];
  const int tt0 = blockIdx.x * 64;
  const int cc0 = blockIdx.y * 32;
  const int b = blockIdx.z;
  const float* xb = x + ((size_t)b * D + cc0) * TLEN + tt0;
#pragma unroll
  for (int i = 0; i < 8; ++i) {
    int idx = threadIdx.x + i * 256;
    lds[idx >> 6][idx & 63] = xb[(size_t)(idx >> 6) * TLEN + (idx & 63)];
  }
  __syncthreads();
  const size_t mrow0 = (size_t)b * 2048 + (tt0 >> 1);
#pragma unroll
  for (int i = 0; i < 8; ++i) {
    int idx = threadIdx.x + i * 256;
    int r = idx >> 6, kk = idx & 63;
    float v = lds[kk >> 1][2 * r + (kk & 1)];
    _Float16 h = (_Float16)v;
    size_t off = (mrow0 + r) * (size_t)KIN + (size_t)cc0 * 2 + kk;
    xh[off] = h;
    xl[off] = (_Float16)(v - (float)h);
  }
}

__global__ __launch_bounds__(256) void k_split(const float* __restrict__ s,
                                               _Float16* __restrict__ hi,
                                               _Float16* __restrict__ lo, int n) {
  int i = blockIdx.x * 256 + threadIdx.x;
  if (i < n) {
    float v = s[i];
    _Float16 h = (_Float16)v;
    hi[i] = h;
    lo[i] = (_Float16)(v - (float)h);
  }
}

__global__ __launch_bounds__(256) void k_tohalf(const float* __restrict__ s,
                                                _Float16* __restrict__ hi, int n) {
  int i = blockIdx.x * 256 + threadIdx.x;
  if (i < n) hi[i] = (_Float16)s[i];
}

__global__ __launch_bounds__(256) void k_e2(const float* __restrict__ embed,
                                            float* __restrict__ e2c) {
  int row = blockIdx.x * 4 + (threadIdx.x >> 6);
  int lane = threadIdx.x & 63;
  const float* er = embed + (size_t)row * D;
  double s = 0.0;
  for (int i = lane; i < D; i += 64) { double v = er[i]; s += v * v; }
#pragma unroll
  for (int mk = 1; mk < 64; mk <<= 1) s += __shfl_xor(s, mk, 64);
  if (lane == 0) e2c[row] = (float)(s - 1024.0);
}

// ---------------- m97-style hh GEMM: 128x128 tile, 4 waves, 16KB LDS, 2-barrier ----
// Single-buffered global_load_lds staging, 4 blocks/CU (inter-block overlap is the
// latency-hiding mechanism — m114/m97). Proven chunk-XOR swizzle on both sides.
// MODE 0: tok epilogue (bias, f16 hi store, ||t||^2).  MODE 1: score top-2 slots.
template <int KDIM, int LOG_GX, int MODE>
__global__ __launch_bounds__(256, 4) void k_gemm_m97(
    const _Float16* __restrict__ A_, const _Float16* __restrict__ B_,
    const float* __restrict__ vec,
    _Float16* __restrict__ outh, float* __restrict__ t2,
    unsigned long long* __restrict__ skKey, float* __restrict__ skSnd) {
  __shared__ _Float16 lds[8192];  // A[128x32] @0 (8KB), B[128x32] @4096 halves
  const int nwg = gridDim.x, bid = blockIdx.x, q = nwg >> 3;
  const int b2 = (bid & 7) * q + (bid >> 3);
  const int nb = b2 & ((1 << LOG_GX) - 1);
  const int n0 = nb * 128, m0 = (b2 >> LOG_GX) * 128;
  const int tid = threadIdx.x, lane = tid & 63, w = tid >> 6;
  const int wr = w >> 1, wc = w & 1, lr = lane & 15, lk = lane >> 4;
  const int cswz8 = (((lane & 3) ^ ((lane >> 3) & 3))) * 8;  // global-side chunk swz
  const int rswz8 = (lk ^ ((lr >> 1) & 3)) * 8;              // read-side chunk swz
  const int g0 = w * 128 + lane, g1 = g0 + 64;
  const int rA0 = g0 >> 2, rA1 = g1 >> 2;
  const int lb0 = (w * 128) * 16, lb1 = (w * 128 + 64) * 16;

  f32x4 acc[4][4] = {};

  for (int kt = 0; kt < KDIM / 32; ++kt) {
    const int k0 = kt * 32;
    gload16(A_ + (size_t)(m0 + rA0) * KDIM + k0 + cswz8, (char*)lds + lb0);
    gload16(A_ + (size_t)(m0 + rA1) * KDIM + k0 + cswz8, (char*)lds + lb1);
    gload16(B_ + (size_t)(n0 + rA0) * KDIM + k0 + cswz8, (char*)lds + 8192 + lb0);
    gload16(B_ + (size_t)(n0 + rA1) * KDIM + k0 + cswz8, (char*)lds + 8192 + lb1);
    __syncthreads();
    half8 ah[4], bh[4];
#pragma unroll
    for (int f = 0; f < 4; ++f) {
      ah[f] = *(const half8*)(lds + (wr * 64 + f * 16 + lr) * 32 + rswz8);
      bh[f] = *(const half8*)(lds + 4096 + (wc * 64 + f * 16 + lr) * 32 + rswz8);
    }
    __builtin_amdgcn_s_setprio(1);
#pragma unroll
    for (int fm = 0; fm < 4; ++fm)
#pragma unroll
      for (int fn = 0; fn < 4; ++fn)
        acc[fm][fn] = __builtin_amdgcn_mfma_f32_16x16x32_f16(ah[fm], bh[fn], acc[fm][fn], 0, 0, 0);
    __builtin_amdgcn_s_setprio(0);
    __syncthreads();
  }

  if constexpr (MODE == 0) {
    // tok epilogue: +bias, store f16 hi, accumulate ||t||^2
#pragma unroll
    for (int fm = 0; fm < 4; ++fm) {
#pragma unroll
      for (int j = 0; j < 4; ++j) {
        int row = wr * 64 + fm * 16 + lk * 4 + j;
        size_t m = (size_t)m0 + row;
        float v2 = 0.f;
#pragma unroll
        for (int fn = 0; fn < 4; ++fn) {
          int col = n0 + wc * 64 + fn * 16 + lr;
          float v = acc[fm][fn][j] + vec[col];
          v2 += v * v;
          outh[m * (size_t)D + col] = (_Float16)v;
        }
#pragma unroll
        for (int mk = 1; mk < 16; mk <<= 1) v2 += __shfl_xor(v2, mk, 64);
        if (lr == 0) atomicAdd(&t2[m], v2);
      }
    }
  } else {
    // score epilogue: top-2 of mval over this wave's 64 codes -> private slot
#pragma unroll
    for (int fm = 0; fm < 4; ++fm) {
#pragma unroll
      for (int j = 0; j < 4; ++j) {
        int row = wr * 64 + fm * 16 + lk * 4 + j;
        size_t m = (size_t)m0 + row;
        float b1 = 3.4e38f, bb2 = 3.4e38f;
        int i1 = 0x7FFFFFFF;
#pragma unroll
        for (int fn = 0; fn < 4; ++fn) {
          int col = n0 + wc * 64 + fn * 16 + lr;
          float mv = vec[col] - 2.0f * acc[fm][fn][j];
          if (mv < b1) { bb2 = b1; b1 = mv; i1 = col; }
          else if (mv < bb2) { bb2 = mv; }
        }
#pragma unroll
        for (int mk = 1; mk < 16; mk <<= 1) {
          float ob1 = __shfl_xor(b1, mk, 64);
          float ob2 = __shfl_xor(bb2, mk, 64);
          int oi = __shfl_xor(i1, mk, 64);
          if (ob1 < b1) { bb2 = fminf(b1, ob2); b1 = ob1; i1 = oi; }
          else { bb2 = fminf(bb2, ob1); }
        }
        if (lr == 0) {
          unsigned long long key = ((unsigned long long)f32_to_key(b1) << 32) | (unsigned)i1;
          skKey[m * 32 + nb * 2 + wc] = key;
          skSnd[m * 32 + nb * 2 + wc] = bb2;
        }
      }
    }
  }
}

// ---------------- flag: global top-2 over 32 slots, margin test, compact ----------------
__global__ __launch_bounds__(256) void k_flag(const unsigned long long* __restrict__ skKey,
                                              const float* __restrict__ skSnd,
                                              unsigned long long* __restrict__ keys,
                                              int* __restrict__ list, int* __restrict__ counter) {
  int m = blockIdx.x * 256 + threadIdx.x;
  unsigned long long best = ~0ull;
  int bsl = 0;
#pragma unroll
  for (int sl = 0; sl < 32; ++sl) {
    unsigned long long k = skKey[(size_t)m * 32 + sl];
    if (k < best) { best = k; bsl = sl; }
  }
  float b1 = key_to_f32((unsigned)(best >> 32));
  float second = skSnd[(size_t)m * 32 + bsl];
#pragma unroll
  for (int sl = 0; sl < 32; ++sl) {
    if (sl != bsl) second = fminf(second, key_to_f32((unsigned)(skKey[(size_t)m * 32 + sl] >> 32)));
  }
  keys[m] = best;
  if (second - b1 < TAU) {
    int p = atomicAdd(counter, 1);
    if (p < CAP) list[p] = m;
  }
}

// ---------------- tok_fix: recompute TRUE tokens (3-product) for flagged rows ----------------
__global__ __launch_bounds__(256) void k_tok_fix(
    const _Float16* __restrict__ xh, const _Float16* __restrict__ xl,
    const _Float16* __restrict__ wh, const _Float16* __restrict__ wl,
    const float* __restrict__ b_in, const int* __restrict__ list,
    const int* __restrict__ counter,
    _Float16* __restrict__ tokh2, _Float16* __restrict__ tokl2) {
  const int count = min(counter[0], CAP);
  const int m0 = blockIdx.y * 128;
  if (m0 >= count) return;
  __shared__ _Float16 sAh[128 * 32], sAl[128 * 32], sBh[128 * 32], sBl[128 * 32];
  const int n0 = blockIdx.x * 128;
  const int tid = threadIdx.x, lane = tid & 63, w = tid >> 6;
  const int wr = w >> 1, wc = w & 1, lr = lane & 15, lk = lane >> 4;
  f32x4 acc[4][4] = {};

  const int g0 = w * 128 + lane, g1 = g0 + 64;
  const int rA0 = g0 >> 2, cA0 = g0 & 3, rA1 = g1 >> 2, cA1 = g1 & 3;
  const int lb0 = (w * 128) * 16, lb1 = (w * 128 + 64) * 16;
  const int tk0 = list[min(m0 + rA0, count - 1)];
  const int tk1 = list[min(m0 + rA1, count - 1)];

  for (int kt = 0; kt < KIN / 32; ++kt) {
    const int k0 = kt * 32;
    gload16(xh + (size_t)tk0 * KIN + k0 + cA0 * 8, (char*)sAh + lb0);
    gload16(xh + (size_t)tk1 * KIN + k0 + cA1 * 8, (char*)sAh + lb1);
    gload16(xl + (size_t)tk0 * KIN + k0 + cA0 * 8, (char*)sAl + lb0);
    gload16(xl + (size_t)tk1 * KIN + k0 + cA1 * 8, (char*)sAl + lb1);
    gload16(wh + (size_t)(n0 + rA0) * KIN + k0 + cA0 * 8, (char*)sBh + lb0);
    gload16(wh + (size_t)(n0 + rA1) * KIN + k0 + cA1 * 8, (char*)sBh + lb1);
    gload16(wl + (size_t)(n0 + rA0) * KIN + k0 + cA0 * 8, (char*)sBl + lb0);
    gload16(wl + (size_t)(n0 + rA1) * KIN + k0 + cA1 * 8, (char*)sBl + lb1);
    __syncthreads();
    half8 ah[4], al2[4], bh[4], bl2[4];
#pragma unroll
    for (int f = 0; f < 4; ++f) {
      ah[f]  = *(const half8*)(sAh + (wr * 64 + f * 16 + lr) * 32 + lk * 8);
      al2[f] = *(const half8*)(sAl + (wr * 64 + f * 16 + lr) * 32 + lk * 8);
      bh[f]  = *(const half8*)(sBh + (wc * 64 + f * 16 + lr) * 32 + lk * 8);
      bl2[f] = *(const half8*)(sBl + (wc * 64 + f * 16 + lr) * 32 + lk * 8);
    }
#pragma unroll
    for (int fm = 0; fm < 4; ++fm)
#pragma unroll
      for (int fn = 0; fn < 4; ++fn) {
        acc[fm][fn] = __builtin_amdgcn_mfma_f32_16x16x32_f16(ah[fm], bh[fn], acc[fm][fn], 0, 0, 0);
        acc[fm][fn] = __builtin_amdgcn_mfma_f32_16x16x32_f16(ah[fm], bl2[fn], acc[fm][fn], 0, 0, 0);
        acc[fm][fn] = __builtin_amdgcn_mfma_f32_16x16x32_f16(al2[fm], bh[fn], acc[fm][fn], 0, 0, 0);
      }
    __syncthreads();
  }
#pragma unroll
  for (int fm = 0; fm < 4; ++fm) {
#pragma unroll
    for (int j = 0; j < 4; ++j) {
      int row = wr * 64 + fm * 16 + lk * 4 + j;
      if (m0 + row >= count) continue;
#pragma unroll
      for (int fn = 0; fn < 4; ++fn) {
        int col = n0 + wc * 64 + fn * 16 + lr;
        float v = acc[fm][fn][j] + b_in[col];
        _Float16 h = (_Float16)v;
        tokh2[(size_t)(m0 + row) * D + col] = h;
        tokl2[(size_t)(m0 + row) * D + col] = (_Float16)(v - (float)h);
      }
    }
  }
}

// ---------------- rescore: 3-product exact scoring of flagged tokens ----------------
__global__ __launch_bounds__(256) void k_rescore(
    const _Float16* __restrict__ tokh2, const _Float16* __restrict__ tokl2,
    const _Float16* __restrict__ eh, const _Float16* __restrict__ el,
    const float* __restrict__ e2c, const int* __restrict__ list,
    const int* __restrict__ counter,
    unsigned long long* __restrict__ keys2) {
  const int count = min(counter[0], CAP);
  const int m0 = blockIdx.y * 128;
  if (m0 >= count) return;
  __shared__ _Float16 sAh[128 * 32], sAl[128 * 32], sBh[128 * 32], sBl[128 * 32];
  const int n0 = blockIdx.x * 128;
  const int tid = threadIdx.x, lane = tid & 63, w = tid >> 6;
  const int wr = w >> 1, wc = w & 1, lr = lane & 15, lk = lane >> 4;
  f32x4 acc[4][4] = {};

  const int g0 = w * 128 + lane, g1 = g0 + 64;
  const int rA0 = g0 >> 2, cA0 = g0 & 3, rA1 = g1 >> 2, cA1 = g1 & 3;
  const int lb0 = (w * 128) * 16, lb1 = (w * 128 + 64) * 16;

  for (int kt = 0; kt < D / 32; ++kt) {
    const int k0 = kt * 32;
    gload16(tokh2 + (size_t)(m0 + rA0) * D + k0 + cA0 * 8, (char*)sAh + lb0);
    gload16(tokh2 + (size_t)(m0 + rA1) * D + k0 + cA1 * 8, (char*)sAh + lb1);
    gload16(tokl2 + (size_t)(m0 + rA0) * D + k0 + cA0 * 8, (char*)sAl + lb0);
    gload16(tokl2 + (size_t)(m0 + rA1) * D + k0 + cA1 * 8, (char*)sAl + lb1);
    gload16(eh + (size_t)(n0 + rA0) * D + k0 + cA0 * 8, (char*)sBh + lb0);
    gload16(eh + (size_t)(n0 + rA1) * D + k0 + cA1 * 8, (char*)sBh + lb1);
    gload16(el + (size_t)(n0 + rA0) * D + k0 + cA0 * 8, (char*)sBl + lb0);
    gload16(el + (size_t)(n0 + rA1) * D + k0 + cA1 * 8, (char*)sBl + lb1);
    __syncthreads();
    half8 ah[4], al2[4], bh[4], bl2[4];
#pragma unroll
    for (int f = 0; f < 4; ++f) {
      ah[f]  = *(const half8*)(sAh + (wr * 64 + f * 16 + lr) * 32 + lk * 8);
      al2[f] = *(const half8*)(sAl + (wr * 64 + f * 16 + lr) * 32 + lk * 8);
      bh[f]  = *(const half8*)(sBh + (wc * 64 + f * 16 + lr) * 32 + lk * 8);
      bl2[f] = *(const half8*)(sBl + (wc * 64 + f * 16 + lr) * 32 + lk * 8);
    }
#pragma unroll
    for (int fm = 0; fm < 4; ++fm)
#pragma unroll
      for (int fn = 0; fn < 4; ++fn) {
        acc[fm][fn] = __builtin_amdgcn_mfma_f32_16x16x32_f16(ah[fm], bh[fn], acc[fm][fn], 0, 0, 0);
        acc[fm][fn] = __builtin_amdgcn_mfma_f32_16x16x32_f16(ah[fm], bl2[fn], acc[fm][fn], 0, 0, 0);
        acc[fm][fn] = __builtin_amdgcn_mfma_f32_16x16x32_f16(al2[fm], bh[fn], acc[fm][fn], 0, 0, 0);
      }
    __syncthreads();
  }
#pragma unroll
  for (int fm = 0; fm < 4; ++fm) {
#pragma unroll
    for (int j = 0; j < 4; ++j) {
      int row = wr * 64 + fm * 16 + lk * 4 + j;
      if (m0 + row >= count) continue;
      int tm = list[m0 + row];
      float best = 3.4e38f;
      int bidx = 0x7FFFFFFF;
#pragma unroll
      for (int fn = 0; fn < 4; ++fn) {
        int col = n0 + wc * 64 + fn * 16 + lr;
        float mv = e2c[col] - 2.0f * acc[fm][fn][j];
        if (mv < best) { best = mv; bidx = col; }
      }
#pragma unroll
      for (int mk = 1; mk < 16; mk <<= 1) {
        float ob = __shfl_xor(best, mk, 64);
        int oi = __shfl_xor(bidx, mk, 64);
        if (ob < best || (ob == best && oi < bidx)) { best = ob; bidx = oi; }
      }
      if (lr == 0) {
        unsigned long long key = ((unsigned long long)f32_to_key(best) << 32) | (unsigned)bidx;
        atomicMin(&keys2[tm], key);
      }
    }
  }
}

__global__ __launch_bounds__(256) void k_merge(unsigned long long* __restrict__ keys,
                                               const unsigned long long* __restrict__ keys2) {
  int m = blockIdx.x * 256 + threadIdx.x;
  unsigned long long k2 = keys2[m];
  if (k2 != ~0ull) keys[m] = k2;
}

// ---------------- GEMM C: out = embed[idx] * w_out^T (R1 structure + swizzle) ----------------
__global__ __launch_bounds__(256) void k_gemm_out(
    const _Float16* __restrict__ eh, const unsigned long long* __restrict__ keys,
    const _Float16* __restrict__ woh, const float* __restrict__ b_out,
    const float* __restrict__ mask, float* __restrict__ out) {
  __shared__ _Float16 sA[128 * 32], sB[128 * 32];
  __shared__ float sC[32 * 129];
  const int n0 = blockIdx.x * 128, m0 = blockIdx.y * 128;
  const int tid = threadIdx.x, lane = tid & 63, w = tid >> 6;
  const int wr = w >> 1, wc = w & 1, lr = lane & 15, lk = lane >> 4;
  const int cswz8 = (((lane & 3) ^ ((lane >> 3) & 3))) * 8;
  const int rswz8 = (lk ^ ((lr >> 1) & 3)) * 8;
  f32x4 acc[4][4] = {};

  const int g0 = w * 128 + lane, g1 = g0 + 64;
  const int rA0 = g0 >> 2, rA1 = g1 >> 2;
  const int lb0 = (w * 128) * 16, lb1 = (w * 128 + 64) * 16;
  const unsigned i0 = (unsigned)(keys[m0 + rA0] & 0xFFFFFFFFull);
  const unsigned i1 = (unsigned)(keys[m0 + rA1] & 0xFFFFFFFFull);
  const _Float16* srcA0 = eh + (size_t)i0 * D + cswz8;
  const _Float16* srcA1 = eh + (size_t)i1 * D + cswz8;

  for (int kt = 0; kt < D / 32; ++kt) {
    const int k0 = kt * 32;
    gload16(srcA0 + k0, (char*)sA + lb0);
    gload16(srcA1 + k0, (char*)sA + lb1);
    gload16(woh + (size_t)(n0 + rA0) * D + k0 + cswz8, (char*)sB + lb0);
    gload16(woh + (size_t)(n0 + rA1) * D + k0 + cswz8, (char*)sB + lb1);
    __syncthreads();
    half8 a[4], b[4];
#pragma unroll
    for (int f = 0; f < 4; ++f) {
      a[f] = *(const half8*)(sA + (wr * 64 + f * 16 + lr) * 32 + rswz8);
      b[f] = *(const half8*)(sB + (wc * 64 + f * 16 + lr) * 32 + rswz8);
    }
#pragma unroll
    for (int fm = 0; fm < 4; ++fm)
#pragma unroll
      for (int fn = 0; fn < 4; ++fn)
        acc[fm][fn] = __builtin_amdgcn_mfma_f32_16x16x32_f16(a[fm], b[fn], acc[fm][fn], 0, 0, 0);
    __syncthreads();
  }
  for (int ch = 0; ch < 4; ++ch) {
    __syncthreads();
    if (wr == (ch >> 1)) {
      int fb = (ch & 1) * 2;
#pragma unroll
      for (int f2 = 0; f2 < 2; ++f2) {
        int fm = fb + f2;
#pragma unroll
        for (int fn = 0; fn < 4; ++fn)
#pragma unroll
          for (int j = 0; j < 4; ++j) {
            int lrow = f2 * 16 + lk * 4 + j;
            int col = wc * 64 + fn * 16 + lr;
            sC[lrow * 129 + col] = acc[fm][fn][j] + b_out[n0 + col];
          }
      }
    }
    __syncthreads();
    const int mbase = m0 + ch * 32;
    const int b = mbase >> 11;
    const int l0 = mbase & 2047;
    const float mval = mask[(size_t)b * TLEN + 2 * l0 + lane];
    for (int oo = 0; oo < 32; ++oo) {
      int ocol = w * 32 + oo;
      float v = sC[(lane >> 1) * 129 + ocol];
      out[((size_t)(b * D + n0 + ocol)) * TLEN + 2 * l0 + lane] = v * mval;
    }
  }
}

// ---------------- loss ----------------
__global__ __launch_bounds__(256) void k_loss(const unsigned long long* __restrict__ keys,
                                              const float* __restrict__ t2,
                                              double* __restrict__ acc) {
  int m = blockIdx.x * 256 + threadIdx.x;
  unsigned long long k = keys[m];
  float mval = key_to_f32((unsigned)(k >> 32));
  double c = (double)mval + 1024.0 + (double)t2[m];
#pragma unroll
  for (int mk = 1; mk < 64; mk <<= 1) c += __shfl_xor(c, mk, 64);
  __shared__ double part[4];
  if ((threadIdx.x & 63) == 0) part[threadIdx.x >> 6] = c;
  __syncthreads();
  if (threadIdx.x == 0) atomicAdd(acc, part[0] + part[1] + part[2] + part[3]);
}

__global__ void k_finalize(const double* __restrict__ acc, float* __restrict__ dst) {
  if (threadIdx.x == 0 && blockIdx.x == 0) *dst = (float)(*acc * (1.0 / 16777216.0));
}

// ---------------- host ----------------
extern "C" void kernel_launch(void* const* d_in, const int* in_sizes, int n_in,
                              void* d_out, int out_size, void* d_ws, size_t ws_size,
                              hipStream_t stream) {
  (void)in_sizes; (void)n_in; (void)out_size;
  const float* x      = (const float*)d_in[0];
  const float* xmask  = (const float*)d_in[1];
  const float* w_in   = (const float*)d_in[2];
  const float* b_in   = (const float*)d_in[3];
  const float* embed  = (const float*)d_in[4];
  const float* w_out  = (const float*)d_in[5];
  const float* b_out  = (const float*)d_in[6];
  float* out = (float*)d_out;

  // x hi/lo splits live in d_out (dead until k_gemm_out; k_tok_fix runs before it)
  _Float16* xh = (_Float16*)d_out;
  _Float16* xl = xh + (size_t)MTOK * KIN;

  char* p = (char*)d_ws;
  auto take = [&](size_t sz) { char* r = p; p += (sz + 255) & ~(size_t)255; return r; };
  _Float16* wh    = (_Float16*)take((size_t)D * KIN * 2);
  _Float16* wl    = (_Float16*)take((size_t)D * KIN * 2);
  _Float16* eh    = (_Float16*)take((size_t)NCODE * D * 2);
  _Float16* el    = (_Float16*)take((size_t)NCODE * D * 2);
  _Float16* woh   = (_Float16*)take((size_t)D * D * 2);
  float* e2c      = (float*)take((size_t)NCODE * 4);
  _Float16* tokh  = (_Float16*)take((size_t)MTOK * D * 2);
  _Float16* tokh2 = (_Float16*)take((size_t)CAP * D * 2);
  _Float16* tokl2 = (_Float16*)take((size_t)CAP * D * 2);
  float* t2       = (float*)take((size_t)MTOK * 4);
  unsigned long long* keys  = (unsigned long long*)take((size_t)MTOK * 8);
  unsigned long long* keys2 = (unsigned long long*)take((size_t)MTOK * 8);
  unsigned long long* skKey = (unsigned long long*)take((size_t)MTOK * 32 * 8);
  float* skSnd    = (float*)take((size_t)MTOK * 32 * 4);
  int* list       = (int*)take((size_t)CAP * 4);
  int* counter    = (int*)take(256);
  double* lossacc = (double*)take(256);
  if ((size_t)(p - (char*)d_ws) > ws_size) return;

  hipMemsetAsync(keys2, 0xFF, (size_t)MTOK * 8, stream);
  hipMemsetAsync(t2, 0, (size_t)MTOK * 4, stream);
  hipMemsetAsync(list, 0, (size_t)CAP * 4, stream);
  hipMemsetAsync(counter, 0, 256, stream);
  hipMemsetAsync(lossacc, 0, 8, stream);

  k_pack_x<<<dim3(64, 32, 8), 256, 0, stream>>>(x, xh, xl);
  k_split<<<(D * KIN + 255) / 256, 256, 0, stream>>>(w_in, wh, wl, D * KIN);
  k_split<<<(NCODE * D + 255) / 256, 256, 0, stream>>>(embed, eh, el, NCODE * D);
  k_tohalf<<<(D * D + 255) / 256, 256, 0, stream>>>(w_out, woh, D * D);
  k_e2<<<NCODE / 4, 256, 0, stream>>>(embed, e2c);

  // tok1: hh-only tokens, M=16384 x N=1024 (128^2 tiles -> 128x8 = 1024 blocks)
  k_gemm_m97<KIN, 3, 0><<<1024, 256, 0, stream>>>(xh, wh, b_in, tokh, t2, nullptr, nullptr);
  // score1: hh-only scores + top-2, M=16384 x N=2048 (128x16 = 2048 blocks)
  k_gemm_m97<D, 4, 1><<<2048, 256, 0, stream>>>(tokh, eh, e2c, nullptr, nullptr, skKey, skSnd);
  k_flag<<<MTOK / 256, 256, 0, stream>>>(skKey, skSnd, keys, list, counter);
  // recompute true tokens for flagged rows, then exact rescore (both count-guarded)
  k_tok_fix<<<dim3(D / 128, CAP / 128), 256, 0, stream>>>(xh, xl, wh, wl, b_in, list, counter, tokh2, tokl2);
  k_rescore<<<dim3(NCODE / 128, CAP / 128), 256, 0, stream>>>(tokh2, tokl2, eh, el, e2c, list, counter, keys2);
  k_merge<<<MTOK / 256, 256, 0, stream>>>(keys, keys2);

  k_gemm_out<<<dim3(D / 128, MTOK / 128), 256, 0, stream>>>(eh, keys, woh, b_out, xmask, out);

  k_loss<<<MTOK / 256, 256, 0, stream>>>(keys, t2, lossacc);
  k_finalize<<<1, 64, 0, stream>>>(lossacc, out + (size_t)MTOK * KIN);
}